// Round 1
// baseline (226.875 us; speedup 1.0000x reference)
//
#include <hip/hip_runtime.h>

#define BATCH 32
#define HDIM 224
#define WDIM 224
#define CDIM 3
#define KTOT (HDIM * WDIM * CDIM)   // 150528
#define HID 64
#define KCHUNK 128
#define NBLK1 (KTOT / KCHUNK)       // 1176
#define PIX (HDIM * WDIM)           // 50176
#define BLK3 49                      // blocks per batch: 1024 thr * 1 px = 1024 px

typedef float float2v __attribute__((ext_vector_type(2)));
typedef float float4v __attribute__((ext_vector_type(4)));
// 4-byte-aligned vector loads (texel addresses are only 4B aligned)
typedef float float4u __attribute__((ext_vector_type(4), aligned(4)));
typedef float float2u __attribute__((ext_vector_type(2), aligned(4)));

// ---------------- Kernel 1: hacc = flat @ w1 (split-K, LDS-staged) ----------
// Block: 256 thr = 4 waves, owns k-range [k0, k0+128). Wave w owns 32 k's,
// split as 2 half-wave k-subranges of 16 (kh = lane>>5). Lane pair-owns 2 hids
// (hp = lane&31 -> hids 2hp, 2hp+1). w1 slice prefetched into regs as float2
// and PINNED with empty asm so the compiler cannot sink the loads into the
// FMA loop (the previous version's VGPR=40 proved it did -> latency-bound).
__global__ __launch_bounds__(256, 4) void k1_gemm(const float* __restrict__ flat,
                                                  const float* __restrict__ w1,
                                                  float* __restrict__ hacc) {
    __shared__ float smem[6144];                 // 24 KB dual-purpose
    const int tid   = threadIdx.x;
    const int lane  = tid & 63;
    const int wave  = tid >> 6;
    const int k0    = blockIdx.x * KCHUNK;
    const int kh    = lane >> 5;                 // which 16-k subrange
    const int hp    = lane & 31;                 // hid pair index
    const int kbase = (wave << 5) + (kh << 4);   // wave*32 + kh*16

    // --- Prefetch w1[k0+kbase .. +16)[2hp, 2hp+1] into regs (16 float2) ---
    float wx[16], wy[16];
    const float* wp = w1 + (size_t)(k0 + kbase) * HID + (hp << 1);
#pragma unroll
    for (int i = 0; i < 16; ++i) {
        const float2v t = *(const float2v*)(wp + (size_t)i * HID);
        wx[i] = t.x; wy[i] = t.y;
    }

    // --- Stage flat[32][k0..k0+128) into LDS (16 KB), coalesced float4 ---
#pragma unroll
    for (int t = 0; t < 4; ++t) {
        const int idx = tid + t * 256;           // 0..1023
        const int b   = idx >> 5;
        const int kq  = idx & 31;
        *(float4v*)(smem + idx * 4) =
            *(const float4v*)(flat + (size_t)b * KTOT + k0 + kq * 4);
    }

    // --- Pin the prefetch in VGPRs: forces residency across the barrier ---
#pragma unroll
    for (int i = 0; i < 16; ++i)
        asm volatile("" : "+v"(wx[i]), "+v"(wy[i]));
    __syncthreads();

    float2v acc[32];
#pragma unroll
    for (int b = 0; b < 32; ++b) { acc[b].x = 0.0f; acc[b].y = 0.0f; }

    // 8 FMAs per ds_read_b128 (4 k x 2 hid), 1024 FMA/thread total
#pragma unroll
    for (int kk = 0; kk < 16; kk += 4) {
#pragma unroll
        for (int b = 0; b < 32; ++b) {
            const float4v x = *(const float4v*)(smem + b * 128 + kbase + kk);
            float2v a = acc[b];
            a.x = fmaf(x.x, wx[kk + 0], a.x);  a.y = fmaf(x.x, wy[kk + 0], a.y);
            a.x = fmaf(x.y, wx[kk + 1], a.x);  a.y = fmaf(x.y, wy[kk + 1], a.y);
            a.x = fmaf(x.z, wx[kk + 2], a.x);  a.y = fmaf(x.z, wy[kk + 2], a.y);
            a.x = fmaf(x.w, wx[kk + 3], a.x);  a.y = fmaf(x.w, wy[kk + 3], a.y);
            acc[b] = a;
        }
    }

    // --- Fold the two kh halves: lanes l and l^32 share (hid-pair, b) ---
#pragma unroll
    for (int b = 0; b < 32; ++b) {
        acc[b].x += __shfl_xor(acc[b].x, 32);
        acc[b].y += __shfl_xor(acc[b].y, 32);
    }

    __syncthreads();                             // flat slice fully consumed
    // --- Waves 1..3 (lower half) dump partials (24 KB); wave 0 reduces ---
    if (wave && kh == 0) {
#pragma unroll
        for (int b = 0; b < 32; ++b)
            *(float2v*)(smem + (wave - 1) * 2048 + b * 64 + (hp << 1)) = acc[b];
    }
    __syncthreads();
    if (wave == 0 && kh == 0) {
#pragma unroll
        for (int b = 0; b < 32; ++b) {
            const int idx = b * 64 + (hp << 1);
            const float2v p0 = *(const float2v*)(smem + idx);
            const float2v p1 = *(const float2v*)(smem + 2048 + idx);
            const float2v p2 = *(const float2v*)(smem + 4096 + idx);
            atomicAdd(hacc + idx,     acc[b].x + p0.x + p1.x + p2.x);
            atomicAdd(hacc + idx + 1, acc[b].y + p0.y + p1.y + p2.y);
        }
    }
}

// -------- Kernel 3: per-wave theta + affine grid + bilinear sampling --------
// 1024 thr/block, 1 px/thread: adjacent lanes sample adjacent texels (the
// transform is ~0.76x zoom), so gathers hit ~10 cache lines/instr instead of
// ~36. Theta is recomputed per wave via shuffle reduction: no LDS, no
// __syncthreads, no 6-serial-lane head section.
__global__ __launch_bounds__(1024) void k3_sample(const float* __restrict__ img,
                                                  const float* __restrict__ hacc,
                                                  const float* __restrict__ b1,
                                                  const float* __restrict__ w2,
                                                  const float* __restrict__ b2,
                                                  float* __restrict__ out) {
    const int b     = blockIdx.x / BLK3;
    const int strip = blockIdx.x - b * BLK3;
    const int tid   = threadIdx.x;
    const int lane  = tid & 63;

    // --- theta, per wave: lane = hid, butterfly-sum the 64-term dot ---
    const float hv = tanhf(hacc[b * HID + lane] + b1[lane]);
    const float* w2p = w2 + lane * 6;            // w2 is [HID][6] row-major
    float q[6];
#pragma unroll
    for (int t = 0; t < 6; ++t) q[t] = hv * w2p[t];
#pragma unroll
    for (int off = 32; off >= 1; off >>= 1) {
#pragma unroll
        for (int t = 0; t < 6; ++t) q[t] += __shfl_xor(q[t], off);
    }
    const float t0 = tanhf(q[0] + b2[0]);
    const float t1 = tanhf(q[1] + b2[1]);
    const float t2 = tanhf(q[2] + b2[2]);
    const float t3 = tanhf(q[3] + b2[3]);
    const float t4 = tanhf(q[4] + b2[4]);
    const float t5 = tanhf(q[5] + b2[5]);

    const float* base = img + (size_t)b * KTOT;
    const int pix = strip * 1024 + tid;
    const int i   = pix / WDIM;
    const int j   = pix - i * WDIM;

    const float xt = (2.0f * (float)j - (float)(WDIM - 1)) / (float)(WDIM - 1);
    const float yt = (2.0f * (float)i - (float)(HDIM - 1)) / (float)(HDIM - 1);

    const float xs = t0 * xt + t1 * yt + t2;
    const float ys = t3 * xt + t4 * yt + t5;

    const float x = 0.5f * (xs + 1.0f) * (float)(WDIM - 1);
    const float y = 0.5f * (ys + 1.0f) * (float)(HDIM - 1);

    const int x0 = (int)floorf(x);
    const int y0 = (int)floorf(y);

    const int x0c = min(max(x0, 0), WDIM - 1);
    const int x1c = min(max(x0 + 1, 0), WDIM - 1);
    const int y0c = min(max(y0, 0), HDIM - 1);
    const int y1c = min(max(y0 + 1, 0), HDIM - 1);

    // Reference computes weights from CLIPPED corner coordinates.
    const float x0f = (float)x0c, x1f = (float)x1c;
    const float y0f = (float)y0c, y1f = (float)y1c;

    const float wa = (x1f - x) * (y1f - y);
    const float wb = (x1f - x) * (y - y0f);
    const float wc = (x - x0f) * (y1f - y);
    const float wd = (x - x0f) * (y - y0f);

    // Both corners of a row are adjacent texels (x1c == x0c+1 whenever the
    // clamp doesn't bind -- always true for this transform); fetch each row
    // as one 16B + one 8B load. min() keeps the tail access in-bounds.
    int oA = (y0c * WDIM + x0c) * 3;
    int oB = (y1c * WDIM + x0c) * 3;
    oA = min(oA, KTOT - 6);
    oB = min(oB, KTOT - 6);
    const float4u Ar  = *(const float4u*)(base + oA);      // a0 a1 a2 c0
    const float2u Ar2 = *(const float2u*)(base + oA + 4);  // c1 c2
    const float4u Br  = *(const float4u*)(base + oB);      // b0 b1 b2 d0
    const float2u Br2 = *(const float2u*)(base + oB + 4);  // d1 d2

    const float r0 = wa * Ar.x + wb * Br.x + wc * Ar.w  + wd * Br.w;
    const float r1 = wa * Ar.y + wb * Br.y + wc * Ar2.x + wd * Br2.x;
    const float r2 = wa * Ar.z + wb * Br.z + wc * Ar2.y + wd * Br2.y;

    float* po = out + (size_t)b * KTOT + (size_t)pix * 3;
    float2u rv; rv.x = r0; rv.y = r1;
    *(float2u*)po = rv;
    po[2] = r2;
}

extern "C" void kernel_launch(void* const* d_in, const int* in_sizes, int n_in,
                              void* d_out, int out_size, void* d_ws, size_t ws_size,
                              hipStream_t stream) {
    const float* inputs = (const float*)d_in[0];
    const float* w1     = (const float*)d_in[1];
    const float* b1     = (const float*)d_in[2];
    const float* w2     = (const float*)d_in[3];
    const float* b2     = (const float*)d_in[4];
    float* out = (float*)d_out;

    float* hacc = (float*)d_ws;                  // 32*64 floats

    hipMemsetAsync(hacc, 0, BATCH * HID * sizeof(float), stream);
    k1_gemm<<<NBLK1, 256, 0, stream>>>(inputs, w1, hacc);
    k3_sample<<<BATCH * BLK3, 1024, 0, stream>>>(inputs, hacc, b1, w2, b2, out);
}

// Round 2
// 145.043 us; speedup vs baseline: 1.5642x; 1.5642x over previous
//
#include <hip/hip_runtime.h>

#define BATCH 32
#define HDIM 224
#define WDIM 224
#define CDIM 3
#define KTOT (HDIM * WDIM * CDIM)   // 150528
#define HID 64
#define KCHUNK 128
#define NBLK1 (KTOT / KCHUNK)       // 1176
#define PIX (HDIM * WDIM)           // 50176
#define BLK3 49                      // blocks per batch: 1024 thr * 1 px = 1024 px

typedef float float4v __attribute__((ext_vector_type(4)));
// 4-byte-aligned vector loads (texel addresses are only 4B aligned)
typedef float float4u __attribute__((ext_vector_type(4), aligned(4)));
typedef float float2u __attribute__((ext_vector_type(2), aligned(4)));

// ---------------- Kernel 1: hacc = flat @ w1 (split-K, LDS-staged) ----------
// Block: 256 thr = 4 waves, owns k-range [k0, k0+128). Wave w owns 32 k's.
// Thread: lane = hid, accumulates all 32 batches. w1 slice prefetched to regs
// BEFORE the staging barrier. The prefetch is pinned with sched_barrier(0)
// (NOT per-value asm -- round 1 proved asm refs into the arrays block SROA and
// send everything to scratch: VGPR=64, WRITE_SIZE=192MB, VALUBusy=0.08%).
// Round 0 (no pin at all) proved the compiler sinks the loads into the FMA
// loop (VGPR=40, VALUBusy=14%, latency-bound at 52us).
__global__ __launch_bounds__(256, 4) void k1_gemm(const float* __restrict__ flat,
                                                  const float* __restrict__ w1,
                                                  float* __restrict__ hacc) {
    __shared__ float smem[6144];                 // 24 KB dual-purpose
    const int tid  = threadIdx.x;
    const int lane = tid & 63;                   // hid
    const int wave = tid >> 6;
    const int k0   = blockIdx.x * KCHUNK;
    const int kw   = wave * 32;

    // --- Prefetch w1[k0+kw .. +32)[lane] into registers (32 indep loads) ---
    float w[32];
    const float* wp = w1 + (size_t)(k0 + kw) * HID + lane;
#pragma unroll
    for (int i = 0; i < 32; ++i)
        w[i] = wp[(size_t)i * HID];

    // --- Stage flat[32][k0..k0+128) into LDS (16 KB), coalesced float4 ---
#pragma unroll
    for (int t = 0; t < 4; ++t) {
        const int idx = tid + t * 256;           // 0..1023; smem addr = idx*4
        const int b   = idx >> 5;
        const int kq  = idx & 31;
        *(float4v*)(smem + idx * 4) =
            *(const float4v*)(flat + (size_t)b * KTOT + k0 + kq * 4);
    }

    // Scheduling fence: every load above must be ISSUED before anything below
    // moves up -- exactly one memory-latency exposure per block.
    __builtin_amdgcn_sched_barrier(0);
    __syncthreads();                             // drains w-prefetch too

    float acc[32];
#pragma unroll
    for (int j = 0; j < 32; ++j) acc[j] = 0.0f;

#pragma unroll
    for (int kk = 0; kk < 32; kk += 4) {
#pragma unroll
        for (int b = 0; b < 32; ++b) {
            const float4v x = *(const float4v*)(smem + b * 128 + kw + kk);
            float a = acc[b];
            a = fmaf(x.x, w[kk + 0], a);
            a = fmaf(x.y, w[kk + 1], a);
            a = fmaf(x.z, w[kk + 2], a);
            a = fmaf(x.w, w[kk + 3], a);
            acc[b] = a;
        }
    }
    __syncthreads();                             // flat slice fully consumed

    // --- Waves 1..3 dump partials (24 KB); wave 0 reduces + atomics ---
    if (wave) {
#pragma unroll
        for (int j = 0; j < 32; ++j)
            smem[(wave - 1) * 2048 + j * 64 + lane] = acc[j];
    }
    __syncthreads();
    if (wave == 0) {
#pragma unroll
        for (int j = 0; j < 32; ++j) {
            const int idx = j * 64 + lane;
            atomicAdd(hacc + idx,
                      acc[j] + smem[idx] + smem[2048 + idx] + smem[4096 + idx]);
        }
    }
}

// -------- Kernel 3: per-wave theta + affine grid + bilinear sampling --------
// 1024 thr/block, 1 px/thread: adjacent lanes sample adjacent texels (the
// transform is ~0.76x zoom), so gathers hit ~12 cache lines/instr. Theta is
// recomputed per wave via shuffle reduction: no LDS, no __syncthreads.
__global__ __launch_bounds__(1024) void k3_sample(const float* __restrict__ img,
                                                  const float* __restrict__ hacc,
                                                  const float* __restrict__ b1,
                                                  const float* __restrict__ w2,
                                                  const float* __restrict__ b2,
                                                  float* __restrict__ out) {
    const int b     = blockIdx.x / BLK3;
    const int strip = blockIdx.x - b * BLK3;
    const int tid   = threadIdx.x;
    const int lane  = tid & 63;

    // --- theta, per wave: lane = hid, butterfly-sum the 64-term dot ---
    const float hv = tanhf(hacc[b * HID + lane] + b1[lane]);
    const float* w2p = w2 + lane * 6;            // w2 is [HID][6] row-major
    float q[6];
#pragma unroll
    for (int t = 0; t < 6; ++t) q[t] = hv * w2p[t];
#pragma unroll
    for (int off = 32; off >= 1; off >>= 1) {
#pragma unroll
        for (int t = 0; t < 6; ++t) q[t] += __shfl_xor(q[t], off);
    }
    const float t0 = tanhf(q[0] + b2[0]);
    const float t1 = tanhf(q[1] + b2[1]);
    const float t2 = tanhf(q[2] + b2[2]);
    const float t3 = tanhf(q[3] + b2[3]);
    const float t4 = tanhf(q[4] + b2[4]);
    const float t5 = tanhf(q[5] + b2[5]);

    const float* base = img + (size_t)b * KTOT;
    const int pix = strip * 1024 + tid;
    const int i   = pix / WDIM;
    const int j   = pix - i * WDIM;

    const float xt = (2.0f * (float)j - (float)(WDIM - 1)) / (float)(WDIM - 1);
    const float yt = (2.0f * (float)i - (float)(HDIM - 1)) / (float)(HDIM - 1);

    const float xs = t0 * xt + t1 * yt + t2;
    const float ys = t3 * xt + t4 * yt + t5;

    const float x = 0.5f * (xs + 1.0f) * (float)(WDIM - 1);
    const float y = 0.5f * (ys + 1.0f) * (float)(HDIM - 1);

    const int x0 = (int)floorf(x);
    const int y0 = (int)floorf(y);

    const int x0c = min(max(x0, 0), WDIM - 1);
    const int x1c = min(max(x0 + 1, 0), WDIM - 1);
    const int y0c = min(max(y0, 0), HDIM - 1);
    const int y1c = min(max(y0 + 1, 0), HDIM - 1);

    // Reference computes weights from CLIPPED corner coordinates.
    const float x0f = (float)x0c, x1f = (float)x1c;
    const float y0f = (float)y0c, y1f = (float)y1c;

    const float wa = (x1f - x) * (y1f - y);
    const float wb = (x1f - x) * (y - y0f);
    const float wc = (x - x0f) * (y1f - y);
    const float wd = (x - x0f) * (y - y0f);

    // Both corners of a row are adjacent texels (x1c == x0c+1 whenever the
    // clamp doesn't bind -- always true for this transform); fetch each row
    // as one 16B + one 8B load. min() keeps the tail access in-bounds.
    int oA = (y0c * WDIM + x0c) * 3;
    int oB = (y1c * WDIM + x0c) * 3;
    oA = min(oA, KTOT - 6);
    oB = min(oB, KTOT - 6);
    const float4u Ar  = *(const float4u*)(base + oA);      // a0 a1 a2 c0
    const float2u Ar2 = *(const float2u*)(base + oA + 4);  // c1 c2
    const float4u Br  = *(const float4u*)(base + oB);      // b0 b1 b2 d0
    const float2u Br2 = *(const float2u*)(base + oB + 4);  // d1 d2

    const float r0 = wa * Ar.x + wb * Br.x + wc * Ar.w  + wd * Br.w;
    const float r1 = wa * Ar.y + wb * Br.y + wc * Ar2.x + wd * Br2.x;
    const float r2 = wa * Ar.z + wb * Br.z + wc * Ar2.y + wd * Br2.y;

    float* po = out + (size_t)b * KTOT + (size_t)pix * 3;
    float2u rv; rv.x = r0; rv.y = r1;
    *(float2u*)po = rv;
    po[2] = r2;
}

extern "C" void kernel_launch(void* const* d_in, const int* in_sizes, int n_in,
                              void* d_out, int out_size, void* d_ws, size_t ws_size,
                              hipStream_t stream) {
    const float* inputs = (const float*)d_in[0];
    const float* w1     = (const float*)d_in[1];
    const float* b1     = (const float*)d_in[2];
    const float* w2     = (const float*)d_in[3];
    const float* b2     = (const float*)d_in[4];
    float* out = (float*)d_out;

    float* hacc = (float*)d_ws;                  // 32*64 floats

    hipMemsetAsync(hacc, 0, BATCH * HID * sizeof(float), stream);
    k1_gemm<<<NBLK1, 256, 0, stream>>>(inputs, w1, hacc);
    k3_sample<<<BATCH * BLK3, 1024, 0, stream>>>(inputs, hacc, b1, w2, b2, out);
}